// Round 10
// baseline (124.009 us; speedup 1.0000x reference)
//
#include <hip/hip_runtime.h>
#include <math.h>

// x: (C,H,W) = (256,512,512) f32.  out = 2 * suffmax_W( suffmax_H( x ) )
// suffmax_W and suffmax_H commute -> per row: W-scan first (independent
// across rows), then the H suffix is a single running max register chained
// bottom-up and stored directly.
//
// R10 structure: ONE WAVE PER CHANNEL. grid = 256 blocks x 64 threads.
// Each lane owns 8 consecutive columns (2 v4f) -> the 512-col W suffix scan
// is entirely in-wave (7 in-lane fmax + shift + 6-step clamped butterfly).
// The H chain is gmax = fmax(gmax, wscanned_row), rows processed bottom-up.
// ZERO __syncthreads, ZERO LDS, ZERO cross-wave traffic: tests whether the
// per-batch block-barrier coupling was the residual ~30% over copy ceiling
// (R4-R9: duration pinned ~110us across cache-policy/traffic variants ->
// not BW-bound; R3: extra waves behind the same barrier useless; R7:
// cross-block sync fatal).
// Pipeline: 8-row chunks, 3-buffer rotation, depth-2 prefetch (32 b128
// loads = 32 KB/CU in flight), rolled x3 loop (static buffer indices).
constexpr int C  = 256;
constexpr int H  = 512;
constexpr int W  = 512;
constexpr int CH = 8;          // rows per chunk
constexpr int NC = H / CH;     // 64 chunks

typedef float v4f __attribute__((ext_vector_type(4)));

__device__ __forceinline__ v4f vmax4(v4f a, v4f b) {
    v4f r;
    r.x = fmaxf(a.x, b.x); r.y = fmaxf(a.y, b.y);
    r.z = fmaxf(a.z, b.z); r.w = fmaxf(a.w, b.w);
    return r;
}

__global__ __launch_bounds__(64, 1)
void tlc_kernel(const float* __restrict__ x, float* __restrict__ out) {
    const int lane = threadIdx.x;          // 0..63
    const int c    = blockIdx.x;
    const int col  = lane * 8;             // first of this lane's 8 columns

    const float* __restrict__ xc = x   + (size_t)c * H * W;
    float*       __restrict__ oc = out + (size_t)c * H * W;

    // clamped source lanes for the suffix butterfly (loop-invariant)
    const int s1  = min(lane + 1, 63),  s2  = min(lane + 2, 63);
    const int s4  = min(lane + 4, 63),  s8  = min(lane + 8, 63);
    const int s16 = min(lane + 16, 63), s32 = min(lane + 32, 63);

    v4f gA = (v4f){-INFINITY, -INFINITY, -INFINITY, -INFINITY};
    v4f gB = gA;                            // running colmax (rows below)

    v4f A0[CH], B0[CH], A1[CH], B1[CH], A2[CH], B2[CH];

// issue chunk t's loads (chunk t = rows [H-CH*(t+1), H-CH*t), bottom-up)
#define LD(Ab, Bb, t) if ((t) < NC) {                                        \
    const float* p0 = xc + (size_t)(H - CH * ((t) + 1)) * W + col;           \
    _Pragma("unroll")                                                        \
    for (int r = 0; r < CH; ++r) {                                           \
        Ab[r] = *(const v4f*)(p0 + (size_t)r * W);                           \
        Bb[r] = *(const v4f*)(p0 + (size_t)r * W + 4);                       \
    } }

// consume chunk t: W-scan all rows in place (independent -> ILP), then chain
// the running H max bottom-up (r = CH-1 .. 0) and store 2*g directly.
#define CP(Ab, Bb, t) {                                                      \
    const int rb = H - CH * ((t) + 1);                                       \
    _Pragma("unroll")                                                        \
    for (int r = 0; r < CH; ++r) {                                           \
        const v4f a = Ab[r], b = Bb[r];                                      \
        const float u7 = b.w;                                                \
        const float u6 = fmaxf(b.z, u7);                                     \
        const float u5 = fmaxf(b.y, u6);                                     \
        const float u4 = fmaxf(b.x, u5);                                     \
        const float u3 = fmaxf(a.w, u4);                                     \
        const float u2 = fmaxf(a.z, u3);                                     \
        const float u1 = fmaxf(a.y, u2);                                     \
        const float u0 = fmaxf(a.x, u1);                                     \
        float e = __shfl(u0, s1);                                            \
        e = (lane == 63) ? -INFINITY : e;                                    \
        e = fmaxf(e, __shfl(e, s1));  e = fmaxf(e, __shfl(e, s2));           \
        e = fmaxf(e, __shfl(e, s4));  e = fmaxf(e, __shfl(e, s8));           \
        e = fmaxf(e, __shfl(e, s16)); e = fmaxf(e, __shfl(e, s32));          \
        Ab[r] = (v4f){fmaxf(u0, e), fmaxf(u1, e), fmaxf(u2, e), fmaxf(u3, e)}; \
        Bb[r] = (v4f){fmaxf(u4, e), fmaxf(u5, e), fmaxf(u6, e), fmaxf(u7, e)}; \
    }                                                                        \
    _Pragma("unroll")                                                        \
    for (int r = CH - 1; r >= 0; --r) {                                      \
        gA = vmax4(gA, Ab[r]);                                               \
        gB = vmax4(gB, Bb[r]);                                               \
        float* q = oc + (size_t)(rb + r) * W + col;                          \
        *(v4f*)q       = gA * 2.0f;                                          \
        *(v4f*)(q + 4) = gB * 2.0f;                                          \
    } }

    // depth-2 pipeline: prologue 2 chunks, then 21 x (load t+2 / compute t)
    // triples (static buffer rotation), tail = chunk 63.
    LD(A0, B0, 0)
    LD(A1, B1, 1)

    for (int k = 0; k < 21; ++k) {
        const int t = 3 * k;
        LD(A2, B2, t + 2)  CP(A0, B0, t)
        LD(A0, B0, t + 3)  CP(A1, B1, t + 1)
        LD(A1, B1, t + 4)  CP(A2, B2, t + 2)
    }
    CP(A0, B0, NC - 1)

#undef LD
#undef CP
}

extern "C" void kernel_launch(void* const* d_in, const int* in_sizes, int n_in,
                              void* d_out, int out_size, void* d_ws, size_t ws_size,
                              hipStream_t stream) {
    const float* x   = (const float*)d_in[0];
    float*       out = (float*)d_out;
    tlc_kernel<<<dim3(C), dim3(64), 0, stream>>>(x, out);
}

// Round 11
// 112.028 us; speedup vs baseline: 1.1070x; 1.1070x over previous
//
#include <hip/hip_runtime.h>
#include <math.h>

// x: (C,H,W) = (256,512,512) f32.  out = 2 * suffmax_W( suffmax_H( x ) )
// suffmax_W and suffmax_H commute -> scan W first (carry-independent), merge
// the H carry elementwise after ONE barrier per batch.
//
// R11: R6 structure + RAW BARRIER. hipcc lowers __syncthreads() to
// "s_waitcnt vmcnt(0) lgkmcnt(0); s_barrier" — the vmcnt(0) drains the
// depth-2 prefetch loads AND the just-issued stores at EVERY batch barrier
// (16x), exposing ~full HBM latency each time. That drain is pure waste
// here: the only cross-wave dependency at the barrier is LDS (ltot/gcol),
// which needs lgkmcnt(0) only. Raw s_barrier + lgkmcnt-only wait keeps
// global loads/stores in flight across barriers (T4: never vmcnt(0) in the
// main loop). This single invariant explains the flat 109-124us surface of
// R4-R10 (depth, cache policy, occupancy, sched_barrier all null).
constexpr int C     = 256;
constexpr int H     = 512;
constexpr int W     = 512;
constexpr int RPW   = 4;            // rows per wave per batch
constexpr int BATCH = 8 * RPW;      // 32 rows/batch
constexpr int NB    = H / BATCH;    // 16 batches

typedef float v4f __attribute__((ext_vector_type(4)));

__device__ __forceinline__ v4f vmax4(v4f a, v4f b) {
    v4f r;
    r.x = fmaxf(a.x, b.x); r.y = fmaxf(a.y, b.y);
    r.z = fmaxf(a.z, b.z); r.w = fmaxf(a.w, b.w);
    return r;
}

// LDS-only barrier: wait for OWN LDS ops (writes visible), then s_barrier.
// No vmcnt drain -> global loads/stores stay outstanding across it.
// sched_barrier(0) after: prevent post-barrier ds_reads from hoisting above
// (rule #18: the barrier intrinsic alone may not fence scheduling).
#define LDS_BARRIER() do {                                                   \
    asm volatile("s_waitcnt lgkmcnt(0)" ::: "memory");                       \
    __builtin_amdgcn_s_barrier();                                            \
    __builtin_amdgcn_sched_barrier(0);                                       \
} while (0)

// One 512-thread block per channel; lane owns 8 consecutive columns so the
// 512-col W suffix scan is one wave (7 in-lane fmax + 7 shuffles). Each wave
// owns 4 rows/batch. 16 batches fully unrolled with a 3-buffer rotation:
// loads for batches t+1 and t+2 stay in flight while batch t computes —
// and now ACROSS the batch barrier too.
__global__ __launch_bounds__(512)
void tlc_kernel(const float* __restrict__ x, float* __restrict__ out) {
    const int tid  = threadIdx.x;
    const int g    = tid >> 6;        // wave 0..7
    const int lane = tid & 63;
    const int c    = blockIdx.x;
    const int col  = lane * 8;        // first of this lane's 8 columns

    __shared__ v4f ltotA[2][8][64], ltotB[2][8][64];  // wave column totals
    __shared__ v4f gcolA[2][64],    gcolB[2][64];     // running colmax

    const float* __restrict__ xc = x   + (size_t)c * H * W;
    float*       __restrict__ oc = out + (size_t)c * H * W;

    const int s1  = min(lane + 1, 63),  s2  = min(lane + 2, 63);
    const int s4  = min(lane + 4, 63),  s8  = min(lane + 8, 63);
    const int s16 = min(lane + 16, 63), s32 = min(lane + 32, 63);

    if (g == 0) {
        const v4f ninf = (v4f){-INFINITY, -INFINITY, -INFINITY, -INFINITY};
        gcolA[0][lane] = ninf;   // ordered before first read by batch-0 barrier
        gcolB[0][lane] = ninf;
    }

    v4f b0A[RPW], b0B[RPW], b1A[RPW], b1B[RPW], b2A[RPW], b2B[RPW];

// issue batch t's loads into buffer `buf` (plain loads: input stays
// LLC-resident across replays, measured FETCH = 131 MB = half input)
#define LOADB(bufA, bufB, t) {                                               \
    const float* p0 = xc + (size_t)(H - BATCH * ((t) + 1) + RPW * g) * W + col; \
    _Pragma("unroll")                                                        \
    for (int r = 0; r < RPW; ++r) {                                          \
        bufA[r] = *(const v4f*)(p0 + (size_t)r * W);                         \
        bufB[r] = *(const v4f*)(p0 + (size_t)r * W + 4);                     \
    } }

// consume buffer = batch t: W-scan in place, local H chain, publish totals,
// ONE LDS-only barrier, elementwise carry merge, plain coalesced store.
#define STEPC(bufA, bufB, t) {                                               \
    const int rb = H - BATCH * ((t) + 1) + RPW * g;                          \
    const int pb = (t) & 1;                                                  \
    _Pragma("unroll")                                                        \
    for (int r = 0; r < RPW; ++r) {                                          \
        const v4f a = bufA[r], b = bufB[r];                                  \
        const float u7 = b.w;                                                \
        const float u6 = fmaxf(b.z, u7);                                     \
        const float u5 = fmaxf(b.y, u6);                                     \
        const float u4 = fmaxf(b.x, u5);                                     \
        const float u3 = fmaxf(a.w, u4);                                     \
        const float u2 = fmaxf(a.z, u3);                                     \
        const float u1 = fmaxf(a.y, u2);                                     \
        const float u0 = fmaxf(a.x, u1);                                     \
        float e = __shfl(u0, s1);                                            \
        e = (lane == 63) ? -INFINITY : e;                                    \
        e = fmaxf(e, __shfl(e, s1));  e = fmaxf(e, __shfl(e, s2));           \
        e = fmaxf(e, __shfl(e, s4));  e = fmaxf(e, __shfl(e, s8));           \
        e = fmaxf(e, __shfl(e, s16)); e = fmaxf(e, __shfl(e, s32));          \
        bufA[r] = (v4f){fmaxf(u0, e), fmaxf(u1, e), fmaxf(u2, e), fmaxf(u3, e)}; \
        bufB[r] = (v4f){fmaxf(u4, e), fmaxf(u5, e), fmaxf(u6, e), fmaxf(u7, e)}; \
    }                                                                        \
    _Pragma("unroll")                                                        \
    for (int r = RPW - 2; r >= 0; --r) {                                     \
        bufA[r] = vmax4(bufA[r], bufA[r + 1]);                               \
        bufB[r] = vmax4(bufB[r], bufB[r + 1]);                               \
    }                                                                        \
    ltotA[pb][g][lane] = bufA[0];                                            \
    ltotB[pb][g][lane] = bufB[0];                                            \
    LDS_BARRIER();                                                           \
    v4f mA = gcolA[pb][lane];                                                \
    v4f mB = gcolB[pb][lane];                                                \
    for (int gg = g + 1; gg < 8; ++gg) {                                     \
        mA = vmax4(mA, ltotA[pb][gg][lane]);                                 \
        mB = vmax4(mB, ltotB[pb][gg][lane]);                                 \
    }                                                                        \
    if (g == 0) {                                                            \
        gcolA[pb ^ 1][lane] = vmax4(bufA[0], mA);                            \
        gcolB[pb ^ 1][lane] = vmax4(bufB[0], mB);                            \
    }                                                                        \
    _Pragma("unroll")                                                        \
    for (int r = 0; r < RPW; ++r) {                                          \
        v4f oA = vmax4(bufA[r], mA) * 2.0f;                                  \
        v4f oB = vmax4(bufB[r], mB) * 2.0f;                                  \
        float* q = oc + (size_t)(rb + r) * W + col;                          \
        *(v4f*)q       = oA;                                                 \
        *(v4f*)(q + 4) = oB;                                                 \
    } }

    // depth-2 pipeline, 3-buffer rotation, fully unrolled (NB = 16)
    LOADB(b0A, b0B, 0)
    LOADB(b1A, b1B, 1)

    LOADB(b2A, b2B,  2)  STEPC(b0A, b0B,  0)
    LOADB(b0A, b0B,  3)  STEPC(b1A, b1B,  1)
    LOADB(b1A, b1B,  4)  STEPC(b2A, b2B,  2)
    LOADB(b2A, b2B,  5)  STEPC(b0A, b0B,  3)
    LOADB(b0A, b0B,  6)  STEPC(b1A, b1B,  4)
    LOADB(b1A, b1B,  7)  STEPC(b2A, b2B,  5)
    LOADB(b2A, b2B,  8)  STEPC(b0A, b0B,  6)
    LOADB(b0A, b0B,  9)  STEPC(b1A, b1B,  7)
    LOADB(b1A, b1B, 10)  STEPC(b2A, b2B,  8)
    LOADB(b2A, b2B, 11)  STEPC(b0A, b0B,  9)
    LOADB(b0A, b0B, 12)  STEPC(b1A, b1B, 10)
    LOADB(b1A, b1B, 13)  STEPC(b2A, b2B, 11)
    LOADB(b2A, b2B, 14)  STEPC(b0A, b0B, 12)
    LOADB(b0A, b0B, 15)  STEPC(b1A, b1B, 13)
                         STEPC(b2A, b2B, 14)
                         STEPC(b0A, b0B, 15)

#undef LOADB
#undef STEPC
}

extern "C" void kernel_launch(void* const* d_in, const int* in_sizes, int n_in,
                              void* d_out, int out_size, void* d_ws, size_t ws_size,
                              hipStream_t stream) {
    const float* x   = (const float*)d_in[0];
    float*       out = (float*)d_out;
    tlc_kernel<<<dim3(C), dim3(512), 0, stream>>>(x, out);
}

// Round 12
// 109.282 us; speedup vs baseline: 1.1348x; 1.0251x over previous
//
#include <hip/hip_runtime.h>
#include <math.h>

// x: (C,H,W) = (256,512,512) f32.  out = 2 * suffmax_W( suffmax_H( x ) )
// suffmax_W and suffmax_H commute -> scan W first (carry-independent), merge
// the H carry elementwise after ONE barrier per batch.
//
// R12 (final combination): R6 structure (champion, 109.5us) = NT loads +
// NT stores + depth-2 3-buffer prefetch, PLUS R11's LDS-only barrier
// (s_waitcnt lgkmcnt(0) + s_barrier, no vmcnt drain) so global loads/stores
// stay in flight across all 16 batch barriers. These two never coexisted.
// Pre-commit: unless <105us, declare roofline (~110us = 74% of the 7 TB/s
// fill-kernel ceiling; minimal traffic 512MB; higher-grid restructures all
// require >=768MB logical -> need >=7TB/s to tie).
constexpr int C     = 256;
constexpr int H     = 512;
constexpr int W     = 512;
constexpr int RPW   = 4;            // rows per wave per batch
constexpr int BATCH = 8 * RPW;      // 32 rows/batch
constexpr int NB    = H / BATCH;    // 16 batches

typedef float v4f __attribute__((ext_vector_type(4)));

__device__ __forceinline__ v4f vmax4(v4f a, v4f b) {
    v4f r;
    r.x = fmaxf(a.x, b.x); r.y = fmaxf(a.y, b.y);
    r.z = fmaxf(a.z, b.z); r.w = fmaxf(a.w, b.w);
    return r;
}

// LDS-only barrier: waits for OWN LDS ops only, then s_barrier. Global
// loads/stores remain outstanding. sched_barrier(0) stops post-barrier LDS
// reads from hoisting above (rule #18).
#define LDS_BARRIER() do {                                                   \
    asm volatile("s_waitcnt lgkmcnt(0)" ::: "memory");                       \
    __builtin_amdgcn_s_barrier();                                            \
    __builtin_amdgcn_sched_barrier(0);                                       \
} while (0)

__global__ __launch_bounds__(512)
void tlc_kernel(const float* __restrict__ x, float* __restrict__ out) {
    const int tid  = threadIdx.x;
    const int g    = tid >> 6;        // wave 0..7
    const int lane = tid & 63;
    const int c    = blockIdx.x;
    const int col  = lane * 8;        // first of this lane's 8 columns

    __shared__ v4f ltotA[2][8][64], ltotB[2][8][64];  // wave column totals
    __shared__ v4f gcolA[2][64],    gcolB[2][64];     // running colmax

    const float* __restrict__ xc = x   + (size_t)c * H * W;
    float*       __restrict__ oc = out + (size_t)c * H * W;

    const int s1  = min(lane + 1, 63),  s2  = min(lane + 2, 63);
    const int s4  = min(lane + 4, 63),  s8  = min(lane + 8, 63);
    const int s16 = min(lane + 16, 63), s32 = min(lane + 32, 63);

    if (g == 0) {
        const v4f ninf = (v4f){-INFINITY, -INFINITY, -INFINITY, -INFINITY};
        gcolA[0][lane] = ninf;   // ordered before first read by batch-0 barrier
        gcolB[0][lane] = ninf;
    }

    v4f b0A[RPW], b0B[RPW], b1A[RPW], b1B[RPW], b2A[RPW], b2B[RPW];

// issue batch t's loads (nontemporal, as in the R6 champion)
#define LOADB(bufA, bufB, t) {                                               \
    const float* p0 = xc + (size_t)(H - BATCH * ((t) + 1) + RPW * g) * W + col; \
    _Pragma("unroll")                                                        \
    for (int r = 0; r < RPW; ++r) {                                          \
        bufA[r] = __builtin_nontemporal_load((const v4f*)(p0 + (size_t)r * W));     \
        bufB[r] = __builtin_nontemporal_load((const v4f*)(p0 + (size_t)r * W + 4)); \
    } }

// consume buffer = batch t: W-scan in place, local H chain, publish totals,
// ONE LDS-only barrier, elementwise carry merge, nontemporal store.
#define STEPC(bufA, bufB, t) {                                               \
    const int rb = H - BATCH * ((t) + 1) + RPW * g;                          \
    const int pb = (t) & 1;                                                  \
    _Pragma("unroll")                                                        \
    for (int r = 0; r < RPW; ++r) {                                          \
        const v4f a = bufA[r], b = bufB[r];                                  \
        const float u7 = b.w;                                                \
        const float u6 = fmaxf(b.z, u7);                                     \
        const float u5 = fmaxf(b.y, u6);                                     \
        const float u4 = fmaxf(b.x, u5);                                     \
        const float u3 = fmaxf(a.w, u4);                                     \
        const float u2 = fmaxf(a.z, u3);                                     \
        const float u1 = fmaxf(a.y, u2);                                     \
        const float u0 = fmaxf(a.x, u1);                                     \
        float e = __shfl(u0, s1);                                            \
        e = (lane == 63) ? -INFINITY : e;                                    \
        e = fmaxf(e, __shfl(e, s1));  e = fmaxf(e, __shfl(e, s2));           \
        e = fmaxf(e, __shfl(e, s4));  e = fmaxf(e, __shfl(e, s8));           \
        e = fmaxf(e, __shfl(e, s16)); e = fmaxf(e, __shfl(e, s32));          \
        bufA[r] = (v4f){fmaxf(u0, e), fmaxf(u1, e), fmaxf(u2, e), fmaxf(u3, e)}; \
        bufB[r] = (v4f){fmaxf(u4, e), fmaxf(u5, e), fmaxf(u6, e), fmaxf(u7, e)}; \
    }                                                                        \
    _Pragma("unroll")                                                        \
    for (int r = RPW - 2; r >= 0; --r) {                                     \
        bufA[r] = vmax4(bufA[r], bufA[r + 1]);                               \
        bufB[r] = vmax4(bufB[r], bufB[r + 1]);                               \
    }                                                                        \
    ltotA[pb][g][lane] = bufA[0];                                            \
    ltotB[pb][g][lane] = bufB[0];                                            \
    LDS_BARRIER();                                                           \
    v4f mA = gcolA[pb][lane];                                                \
    v4f mB = gcolB[pb][lane];                                                \
    for (int gg = g + 1; gg < 8; ++gg) {                                     \
        mA = vmax4(mA, ltotA[pb][gg][lane]);                                 \
        mB = vmax4(mB, ltotB[pb][gg][lane]);                                 \
    }                                                                        \
    if (g == 0) {                                                            \
        gcolA[pb ^ 1][lane] = vmax4(bufA[0], mA);                            \
        gcolB[pb ^ 1][lane] = vmax4(bufB[0], mB);                            \
    }                                                                        \
    _Pragma("unroll")                                                        \
    for (int r = 0; r < RPW; ++r) {                                          \
        v4f oA = vmax4(bufA[r], mA) * 2.0f;                                  \
        v4f oB = vmax4(bufB[r], mB) * 2.0f;                                  \
        float* q = oc + (size_t)(rb + r) * W + col;                          \
        __builtin_nontemporal_store(oA, (v4f*)q);                            \
        __builtin_nontemporal_store(oB, (v4f*)(q + 4));                      \
    } }

    // depth-2 pipeline, 3-buffer rotation, fully unrolled (NB = 16)
    LOADB(b0A, b0B, 0)
    LOADB(b1A, b1B, 1)

    LOADB(b2A, b2B,  2)  STEPC(b0A, b0B,  0)
    LOADB(b0A, b0B,  3)  STEPC(b1A, b1B,  1)
    LOADB(b1A, b1B,  4)  STEPC(b2A, b2B,  2)
    LOADB(b2A, b2B,  5)  STEPC(b0A, b0B,  3)
    LOADB(b0A, b0B,  6)  STEPC(b1A, b1B,  4)
    LOADB(b1A, b1B,  7)  STEPC(b2A, b2B,  5)
    LOADB(b2A, b2B,  8)  STEPC(b0A, b0B,  6)
    LOADB(b0A, b0B,  9)  STEPC(b1A, b1B,  7)
    LOADB(b1A, b1B, 10)  STEPC(b2A, b2B,  8)
    LOADB(b2A, b2B, 11)  STEPC(b0A, b0B,  9)
    LOADB(b0A, b0B, 12)  STEPC(b1A, b1B, 10)
    LOADB(b1A, b1B, 13)  STEPC(b2A, b2B, 11)
    LOADB(b2A, b2B, 14)  STEPC(b0A, b0B, 12)
    LOADB(b0A, b0B, 15)  STEPC(b1A, b1B, 13)
                         STEPC(b2A, b2B, 14)
                         STEPC(b0A, b0B, 15)

#undef LOADB
#undef STEPC
}

extern "C" void kernel_launch(void* const* d_in, const int* in_sizes, int n_in,
                              void* d_out, int out_size, void* d_ws, size_t ws_size,
                              hipStream_t stream) {
    const float* x   = (const float*)d_in[0];
    float*       out = (float*)d_out;
    tlc_kernel<<<dim3(C), dim3(512), 0, stream>>>(x, out);
}